// Round 2
// baseline (927.700 us; speedup 1.0000x reference)
//
#include <hip/hip_runtime.h>

// Trilinear sampling of tsdf/weights volumes at M = B*H*N points.
// D = 256 fixed (reference). Outputs concatenated flat in d_out as float32:
//   [0,        M)   fusion_values
//   [M,      25M)   indices  (M,8,3) -- stored as float-valued integers
//   [25M,    33M)   weights  (M,8)
//   [33M,    34M)   fusion_weights
//
// v2b: non-temporal (evict-first) hints on all streamed traffic.
//   - Output (403 MB/iter, write-once) and points (33 MB/iter, read-once)
//     were thrashing the 256 MB Infinity Cache every iteration, evicting
//     the 134 MB tsdf+weights working set, forcing the 16 random gathers
//     per point out to HBM. `nt` keeps the volumes IF-resident.
//   - Uses clang ext_vector_type for 16B nt stores (HIP float4 is a class
//     type the builtin rejects).

typedef float v4f __attribute__((ext_vector_type(4)));

__global__ __launch_bounds__(256) void extractor_kernel(
    const float* __restrict__ points,
    const float* __restrict__ tsdf,
    const float* __restrict__ wvol,
    float* __restrict__ out,
    int M)
{
    const int m = blockIdx.x * 256 + threadIdx.x;
    if (m >= M) return;

    const size_t p3 = 3ull * (size_t)m;
    const float px = __builtin_nontemporal_load(points + p3 + 0);
    const float py = __builtin_nontemporal_load(points + p3 + 1);
    const float pz = __builtin_nontemporal_load(points + p3 + 2);

    const float fx = floorf(px), fy = floorf(py), fz = floorf(pz);
    const int bx = (int)fx, by = (int)fy, bz = (int)fz;

    // center - p ; sign gives neighbor direction, |.| gives alpha
    const float dxc = fx + 0.5f - px;
    const float dyc = fy + 0.5f - py;
    const float dzc = fz + 0.5f - pz;

    const int nx = (dxc > 0.f) ? 1 : ((dxc < 0.f) ? -1 : 0);
    const int ny = (dyc > 0.f) ? 1 : ((dyc < 0.f) ? -1 : 0);
    const int nz = (dzc > 0.f) ? 1 : ((dzc < 0.f) ? -1 : 0);

    const float ax = fabsf(dxc), ay = fabsf(dyc), az = fabsf(dzc);
    const float axi = 1.f - ax, ayi = 1.f - ay, azi = 1.f - az;

    float fv = 0.f, fw = 0.f;
    float idxf[24];
    float wts[8];

#pragma unroll
    for (int c = 0; c < 8; ++c) {
        const int ox = (c >> 2) & 1;
        const int oy = (c >> 1) & 1;
        const int oz = c & 1;
        const int cx = bx + (ox ? nx : 0);
        const int cy = by + (oy ? ny : 0);
        const int cz = bz + (oz ? nz : 0);
        const float w = (ox ? ax : axi) * (oy ? ay : ayi) * (oz ? az : azi);
        const bool valid = ((unsigned)cx < 256u) & ((unsigned)cy < 256u) & ((unsigned)cz < 256u);
        const int ccx = min(max(cx, 0), 255);
        const int ccy = min(max(cy, 0), 255);
        const int ccz = min(max(cz, 0), 255);
        const int flat = (ccx << 16) | (ccy << 8) | ccz;
        const float vm = valid ? 1.f : 0.f;
        // gathers stay cached (want L2/IF residency for the volumes)
        const float tv = tsdf[flat] * vm;
        const float wv = wvol[flat] * vm;
        fv += tv * w;
        fw += wv * w;
        idxf[c * 3 + 0] = (float)cx;
        idxf[c * 3 + 1] = (float)cy;
        idxf[c * 3 + 2] = (float)cz;
        wts[c] = w;
    }

    const size_t Ms = (size_t)M;
    __builtin_nontemporal_store(fv, out + m);
    __builtin_nontemporal_store(fw, out + 33 * Ms + m);

    // indices block: 24 floats/thread, 96 B, 16B-aligned (M % 4 == 0)
    v4f* __restrict__ oi = reinterpret_cast<v4f*>(out + Ms + (size_t)m * 24);
    const v4f* ii = reinterpret_cast<const v4f*>(idxf);
#pragma unroll
    for (int i = 0; i < 6; ++i) __builtin_nontemporal_store(ii[i], oi + i);

    // weights block: 8 floats/thread, 32 B
    v4f* __restrict__ ow = reinterpret_cast<v4f*>(out + 25 * Ms + (size_t)m * 8);
    const v4f* wi = reinterpret_cast<const v4f*>(wts);
    __builtin_nontemporal_store(wi[0], ow + 0);
    __builtin_nontemporal_store(wi[1], ow + 1);
}

extern "C" void kernel_launch(void* const* d_in, const int* in_sizes, int n_in,
                              void* d_out, int out_size, void* d_ws, size_t ws_size,
                              hipStream_t stream) {
    const float* points = (const float*)d_in[0];
    const float* tsdf   = (const float*)d_in[1];
    const float* wvol   = (const float*)d_in[2];
    float* out = (float*)d_out;

    const int M = in_sizes[0] / 3;               // B*H*N
    const int blocks = (M + 255) / 256;
    extractor_kernel<<<blocks, 256, 0, stream>>>(points, tsdf, wvol, out, M);
}

// Round 3
// 712.278 us; speedup vs baseline: 1.3024x; 1.3024x over previous
//
#include <hip/hip_runtime.h>

// Trilinear sampling of tsdf/weights volumes at M = B*H*N points.
// D = 256 fixed (reference). Outputs concatenated flat in d_out as float32:
//   [0,        M)   fusion_values
//   [M,      25M)   indices  (M,8,3) -- stored as float-valued integers
//   [25M,    33M)   weights  (M,8)
//   [33M,    34M)   fusion_weights
//
// v3: fuse the two volumes into one interleaved (tsdf,wvol) float2 array in
//   the workspace (pack pre-pass, every launch -- re-poison safe). The 8
//   corner gathers then pull both values from the SAME cache lines: line
//   touches per point halve (measured gather fetch was 508 B/pt; predict
//   ~250 B/pt). Pack is pure streaming (268 MB ~= 50 us).
//   nt hints from v2 removed: they inflated WRITE_SIZE 1.54x (partial-line
//   evictions on the scattered index stores) and didn't move FETCH.

typedef float v2f __attribute__((ext_vector_type(2)));
typedef float v4f __attribute__((ext_vector_type(4)));

__global__ __launch_bounds__(256) void pack_kernel(
    const float* __restrict__ tsdf,
    const float* __restrict__ wvol,
    float* __restrict__ packed,      // 2 * 256^3 floats, interleaved t,w
    int n4)                          // 256^3 / 4
{
    const int i = blockIdx.x * 256 + threadIdx.x;
    if (i >= n4) return;
    const v4f t = *reinterpret_cast<const v4f*>(tsdf + 4ull * (size_t)i);
    const v4f w = *reinterpret_cast<const v4f*>(wvol + 4ull * (size_t)i);
    v4f a; a.x = t.x; a.y = w.x; a.z = t.y; a.w = w.y;
    v4f b; b.x = t.z; b.y = w.z; b.z = t.w; b.w = w.w;
    v4f* __restrict__ dst = reinterpret_cast<v4f*>(packed + 8ull * (size_t)i);
    dst[0] = a;
    dst[1] = b;
}

__global__ __launch_bounds__(256) void extractor_packed(
    const float* __restrict__ points,
    const float* __restrict__ packed,
    float* __restrict__ out,
    int M)
{
    const int m = blockIdx.x * 256 + threadIdx.x;
    if (m >= M) return;

    const size_t p3 = 3ull * (size_t)m;
    const float px = points[p3 + 0];
    const float py = points[p3 + 1];
    const float pz = points[p3 + 2];

    const float fx = floorf(px), fy = floorf(py), fz = floorf(pz);
    const int bx = (int)fx, by = (int)fy, bz = (int)fz;

    const float dxc = fx + 0.5f - px;
    const float dyc = fy + 0.5f - py;
    const float dzc = fz + 0.5f - pz;

    const int nx = (dxc > 0.f) ? 1 : ((dxc < 0.f) ? -1 : 0);
    const int ny = (dyc > 0.f) ? 1 : ((dyc < 0.f) ? -1 : 0);
    const int nz = (dzc > 0.f) ? 1 : ((dzc < 0.f) ? -1 : 0);

    const float ax = fabsf(dxc), ay = fabsf(dyc), az = fabsf(dzc);
    const float axi = 1.f - ax, ayi = 1.f - ay, azi = 1.f - az;

    float fv = 0.f, fw = 0.f;
    float idxf[24];
    float wts[8];

#pragma unroll
    for (int c = 0; c < 8; ++c) {
        const int ox = (c >> 2) & 1;
        const int oy = (c >> 1) & 1;
        const int oz = c & 1;
        const int cx = bx + (ox ? nx : 0);
        const int cy = by + (oy ? ny : 0);
        const int cz = bz + (oz ? nz : 0);
        const float w = (ox ? ax : axi) * (oy ? ay : ayi) * (oz ? az : azi);
        const bool valid = ((unsigned)cx < 256u) & ((unsigned)cy < 256u) & ((unsigned)cz < 256u);
        const int ccx = min(max(cx, 0), 255);
        const int ccy = min(max(cy, 0), 255);
        const int ccz = min(max(cz, 0), 255);
        const int flat = (ccx << 16) | (ccy << 8) | ccz;
        const float vm = valid ? 1.f : 0.f;
        const v2f tw = *reinterpret_cast<const v2f*>(packed + 2ull * (size_t)flat);
        fv += tw.x * vm * w;
        fw += tw.y * vm * w;
        idxf[c * 3 + 0] = (float)cx;
        idxf[c * 3 + 1] = (float)cy;
        idxf[c * 3 + 2] = (float)cz;
        wts[c] = w;
    }

    const size_t Ms = (size_t)M;
    out[m] = fv;
    out[33 * Ms + m] = fw;

    float4* __restrict__ oi = reinterpret_cast<float4*>(out + Ms + (size_t)m * 24);
    const float4* ii = reinterpret_cast<const float4*>(idxf);
#pragma unroll
    for (int i = 0; i < 6; ++i) oi[i] = ii[i];

    float4* __restrict__ ow = reinterpret_cast<float4*>(out + 25 * Ms + (size_t)m * 8);
    const float4* wi = reinterpret_cast<const float4*>(wts);
    ow[0] = wi[0];
    ow[1] = wi[1];
}

// Fallback (v1 baseline) if workspace is too small for the packed array.
__global__ __launch_bounds__(256) void extractor_kernel(
    const float* __restrict__ points,
    const float* __restrict__ tsdf,
    const float* __restrict__ wvol,
    float* __restrict__ out,
    int M)
{
    const int m = blockIdx.x * 256 + threadIdx.x;
    if (m >= M) return;

    const size_t p3 = 3ull * (size_t)m;
    const float px = points[p3 + 0];
    const float py = points[p3 + 1];
    const float pz = points[p3 + 2];

    const float fx = floorf(px), fy = floorf(py), fz = floorf(pz);
    const int bx = (int)fx, by = (int)fy, bz = (int)fz;

    const float dxc = fx + 0.5f - px;
    const float dyc = fy + 0.5f - py;
    const float dzc = fz + 0.5f - pz;

    const int nx = (dxc > 0.f) ? 1 : ((dxc < 0.f) ? -1 : 0);
    const int ny = (dyc > 0.f) ? 1 : ((dyc < 0.f) ? -1 : 0);
    const int nz = (dzc > 0.f) ? 1 : ((dzc < 0.f) ? -1 : 0);

    const float ax = fabsf(dxc), ay = fabsf(dyc), az = fabsf(dzc);
    const float axi = 1.f - ax, ayi = 1.f - ay, azi = 1.f - az;

    float fv = 0.f, fw = 0.f;
    float idxf[24];
    float wts[8];

#pragma unroll
    for (int c = 0; c < 8; ++c) {
        const int ox = (c >> 2) & 1;
        const int oy = (c >> 1) & 1;
        const int oz = c & 1;
        const int cx = bx + (ox ? nx : 0);
        const int cy = by + (oy ? ny : 0);
        const int cz = bz + (oz ? nz : 0);
        const float w = (ox ? ax : axi) * (oy ? ay : ayi) * (oz ? az : azi);
        const bool valid = ((unsigned)cx < 256u) & ((unsigned)cy < 256u) & ((unsigned)cz < 256u);
        const int ccx = min(max(cx, 0), 255);
        const int ccy = min(max(cy, 0), 255);
        const int ccz = min(max(cz, 0), 255);
        const int flat = (ccx << 16) | (ccy << 8) | ccz;
        const float vm = valid ? 1.f : 0.f;
        const float tv = tsdf[flat] * vm;
        const float wv = wvol[flat] * vm;
        fv += tv * w;
        fw += wv * w;
        idxf[c * 3 + 0] = (float)cx;
        idxf[c * 3 + 1] = (float)cy;
        idxf[c * 3 + 2] = (float)cz;
        wts[c] = w;
    }

    const size_t Ms = (size_t)M;
    out[m] = fv;
    out[33 * Ms + m] = fw;

    float4* __restrict__ oi = reinterpret_cast<float4*>(out + Ms + (size_t)m * 24);
    const float4* ii = reinterpret_cast<const float4*>(idxf);
#pragma unroll
    for (int i = 0; i < 6; ++i) oi[i] = ii[i];

    float4* __restrict__ ow = reinterpret_cast<float4*>(out + 25 * Ms + (size_t)m * 8);
    const float4* wi = reinterpret_cast<const float4*>(wts);
    ow[0] = wi[0];
    ow[1] = wi[1];
}

extern "C" void kernel_launch(void* const* d_in, const int* in_sizes, int n_in,
                              void* d_out, int out_size, void* d_ws, size_t ws_size,
                              hipStream_t stream) {
    const float* points = (const float*)d_in[0];
    const float* tsdf   = (const float*)d_in[1];
    const float* wvol   = (const float*)d_in[2];
    float* out = (float*)d_out;

    const int M = in_sizes[0] / 3;               // B*H*N
    const int blocks = (M + 255) / 256;

    const size_t nvox = 256ull * 256ull * 256ull;
    const size_t needed = nvox * 2ull * sizeof(float);   // 134 MB

    if (ws_size >= needed) {
        float* packed = (float*)d_ws;
        const int n4 = (int)(nvox / 4);                  // 4 voxels/thread
        pack_kernel<<<(n4 + 255) / 256, 256, 0, stream>>>(tsdf, wvol, packed, n4);
        extractor_packed<<<blocks, 256, 0, stream>>>(points, packed, out, M);
    } else {
        extractor_kernel<<<blocks, 256, 0, stream>>>(points, tsdf, wvol, out, M);
    }
}

// Round 4
// 705.083 us; speedup vs baseline: 1.3157x; 1.0102x over previous
//
#include <hip/hip_runtime.h>

// Trilinear sampling of tsdf/weights volumes at M = B*H*N points.
// D = 256 fixed (reference). Outputs concatenated flat in d_out as float32:
//   [0,        M)   fusion_values
//   [M,      25M)   indices  (M,8,3) -- stored as float-valued integers
//   [25M,    33M)   weights  (M,8)
//   [33M,    34M)   fusion_weights
//
// v4: packed volume is stored as 2x2x2 BRICKS of interleaved (t,w) pairs.
//   One brick = 8 voxels x 8 B = exactly one 64 B sector. The 2x2x2 corner
//   stencil touches E[1.5^3]=3.375 bricks instead of 4 row-sectors
//   (measured v3: 3.99 x 64 B/pt, zero reuse, 64 B fetch granularity).
//   Pack kernel is one-thread-per-brick: coalesced 8 B reads, each thread
//   writes its brick's full 64 B line within one wave (no partial-line
//   writeback -- the v2 nt-store lesson).

typedef float v2f __attribute__((ext_vector_type(2)));
typedef float v4f __attribute__((ext_vector_type(4)));

__global__ __launch_bounds__(256) void pack_brick_kernel(
    const float* __restrict__ tsdf,
    const float* __restrict__ wvol,
    float* __restrict__ packed)      // 128^3 bricks * 16 floats
{
    const int t = blockIdx.x * 256 + threadIdx.x;   // brick id, 128^3 total
    const int bz = t & 127;
    const int by = (t >> 7) & 127;
    const int bx = t >> 14;
    const int x0 = bx << 1, y0 = by << 1, z0 = bz << 1;

    v4f o[4];
#pragma unroll
    for (int dx = 0; dx < 2; ++dx) {
#pragma unroll
        for (int dy = 0; dy < 2; ++dy) {
            const size_t src = ((size_t)(x0 + dx) << 16) |
                               (size_t)((y0 + dy) << 8) | (size_t)z0;
            const v2f tp = *reinterpret_cast<const v2f*>(tsdf + src);
            const v2f wp = *reinterpret_cast<const v2f*>(wvol + src);
            v4f o4; o4.x = tp.x; o4.y = wp.x; o4.z = tp.y; o4.w = wp.y;
            o[dx * 2 + dy] = o4;    // voxel offsets (dx,dy,0..1) = floats dx*8+dy*4..+3
        }
    }
    v4f* __restrict__ dst = reinterpret_cast<v4f*>(packed + ((size_t)t << 4));
    dst[0] = o[0];
    dst[1] = o[1];
    dst[2] = o[2];
    dst[3] = o[3];
}

__global__ __launch_bounds__(256) void extractor_packed(
    const float* __restrict__ points,
    const float* __restrict__ packed,
    float* __restrict__ out,
    int M)
{
    const int m = blockIdx.x * 256 + threadIdx.x;
    if (m >= M) return;

    const size_t p3 = 3ull * (size_t)m;
    const float px = points[p3 + 0];
    const float py = points[p3 + 1];
    const float pz = points[p3 + 2];

    const float fx = floorf(px), fy = floorf(py), fz = floorf(pz);
    const int bx = (int)fx, by = (int)fy, bz = (int)fz;

    const float dxc = fx + 0.5f - px;
    const float dyc = fy + 0.5f - py;
    const float dzc = fz + 0.5f - pz;

    const int nx = (dxc > 0.f) ? 1 : ((dxc < 0.f) ? -1 : 0);
    const int ny = (dyc > 0.f) ? 1 : ((dyc < 0.f) ? -1 : 0);
    const int nz = (dzc > 0.f) ? 1 : ((dzc < 0.f) ? -1 : 0);

    const float ax = fabsf(dxc), ay = fabsf(dyc), az = fabsf(dzc);
    const float axi = 1.f - ax, ayi = 1.f - ay, azi = 1.f - az;

    float fv = 0.f, fw = 0.f;
    float idxf[24];
    float wts[8];

#pragma unroll
    for (int c = 0; c < 8; ++c) {
        const int ox = (c >> 2) & 1;
        const int oy = (c >> 1) & 1;
        const int oz = c & 1;
        const int cx = bx + (ox ? nx : 0);
        const int cy = by + (oy ? ny : 0);
        const int cz = bz + (oz ? nz : 0);
        const float w = (ox ? ax : axi) * (oy ? ay : ayi) * (oz ? az : azi);
        const bool valid = ((unsigned)cx < 256u) & ((unsigned)cy < 256u) & ((unsigned)cz < 256u);
        const int ccx = min(max(cx, 0), 255);
        const int ccy = min(max(cy, 0), 255);
        const int ccz = min(max(cz, 0), 255);
        // brick addressing: brick = (ccx>>1, ccy>>1, ccz>>1), 16 floats/brick
        const int brick = ((ccx >> 1) << 14) | ((ccy >> 1) << 7) | (ccz >> 1);
        const int off = ((ccx & 1) << 2) | ((ccy & 1) << 1) | (ccz & 1);
        const size_t fidx = ((size_t)brick << 4) + (size_t)(off << 1);
        const float vm = valid ? 1.f : 0.f;
        const v2f tw = *reinterpret_cast<const v2f*>(packed + fidx);
        fv += tw.x * vm * w;
        fw += tw.y * vm * w;
        idxf[c * 3 + 0] = (float)cx;
        idxf[c * 3 + 1] = (float)cy;
        idxf[c * 3 + 2] = (float)cz;
        wts[c] = w;
    }

    const size_t Ms = (size_t)M;
    out[m] = fv;
    out[33 * Ms + m] = fw;

    float4* __restrict__ oi = reinterpret_cast<float4*>(out + Ms + (size_t)m * 24);
    const float4* ii = reinterpret_cast<const float4*>(idxf);
#pragma unroll
    for (int i = 0; i < 6; ++i) oi[i] = ii[i];

    float4* __restrict__ ow = reinterpret_cast<float4*>(out + 25 * Ms + (size_t)m * 8);
    const float4* wi = reinterpret_cast<const float4*>(wts);
    ow[0] = wi[0];
    ow[1] = wi[1];
}

// Fallback (v1 baseline) if workspace is too small for the packed array.
__global__ __launch_bounds__(256) void extractor_kernel(
    const float* __restrict__ points,
    const float* __restrict__ tsdf,
    const float* __restrict__ wvol,
    float* __restrict__ out,
    int M)
{
    const int m = blockIdx.x * 256 + threadIdx.x;
    if (m >= M) return;

    const size_t p3 = 3ull * (size_t)m;
    const float px = points[p3 + 0];
    const float py = points[p3 + 1];
    const float pz = points[p3 + 2];

    const float fx = floorf(px), fy = floorf(py), fz = floorf(pz);
    const int bx = (int)fx, by = (int)fy, bz = (int)fz;

    const float dxc = fx + 0.5f - px;
    const float dyc = fy + 0.5f - py;
    const float dzc = fz + 0.5f - pz;

    const int nx = (dxc > 0.f) ? 1 : ((dxc < 0.f) ? -1 : 0);
    const int ny = (dyc > 0.f) ? 1 : ((dyc < 0.f) ? -1 : 0);
    const int nz = (dzc > 0.f) ? 1 : ((dzc < 0.f) ? -1 : 0);

    const float ax = fabsf(dxc), ay = fabsf(dyc), az = fabsf(dzc);
    const float axi = 1.f - ax, ayi = 1.f - ay, azi = 1.f - az;

    float fv = 0.f, fw = 0.f;
    float idxf[24];
    float wts[8];

#pragma unroll
    for (int c = 0; c < 8; ++c) {
        const int ox = (c >> 2) & 1;
        const int oy = (c >> 1) & 1;
        const int oz = c & 1;
        const int cx = bx + (ox ? nx : 0);
        const int cy = by + (oy ? ny : 0);
        const int cz = bz + (oz ? nz : 0);
        const float w = (ox ? ax : axi) * (oy ? ay : ayi) * (oz ? az : azi);
        const bool valid = ((unsigned)cx < 256u) & ((unsigned)cy < 256u) & ((unsigned)cz < 256u);
        const int ccx = min(max(cx, 0), 255);
        const int ccy = min(max(cy, 0), 255);
        const int ccz = min(max(cz, 0), 255);
        const int flat = (ccx << 16) | (ccy << 8) | ccz;
        const float vm = valid ? 1.f : 0.f;
        const float tv = tsdf[flat] * vm;
        const float wv = wvol[flat] * vm;
        fv += tv * w;
        fw += wv * w;
        idxf[c * 3 + 0] = (float)cx;
        idxf[c * 3 + 1] = (float)cy;
        idxf[c * 3 + 2] = (float)cz;
        wts[c] = w;
    }

    const size_t Ms = (size_t)M;
    out[m] = fv;
    out[33 * Ms + m] = fw;

    float4* __restrict__ oi = reinterpret_cast<float4*>(out + Ms + (size_t)m * 24);
    const float4* ii = reinterpret_cast<const float4*>(idxf);
#pragma unroll
    for (int i = 0; i < 6; ++i) oi[i] = ii[i];

    float4* __restrict__ ow = reinterpret_cast<float4*>(out + 25 * Ms + (size_t)m * 8);
    const float4* wi = reinterpret_cast<const float4*>(wts);
    ow[0] = wi[0];
    ow[1] = wi[1];
}

extern "C" void kernel_launch(void* const* d_in, const int* in_sizes, int n_in,
                              void* d_out, int out_size, void* d_ws, size_t ws_size,
                              hipStream_t stream) {
    const float* points = (const float*)d_in[0];
    const float* tsdf   = (const float*)d_in[1];
    const float* wvol   = (const float*)d_in[2];
    float* out = (float*)d_out;

    const int M = in_sizes[0] / 3;               // B*H*N
    const int blocks = (M + 255) / 256;

    const size_t nvox = 256ull * 256ull * 256ull;
    const size_t needed = nvox * 2ull * sizeof(float);   // 134 MB

    if (ws_size >= needed) {
        float* packed = (float*)d_ws;
        const int nbricks = 128 * 128 * 128;             // 2,097,152
        pack_brick_kernel<<<nbricks / 256, 256, 0, stream>>>(tsdf, wvol, packed);
        extractor_packed<<<blocks, 256, 0, stream>>>(points, packed, out, M);
    } else {
        extractor_kernel<<<blocks, 256, 0, stream>>>(points, tsdf, wvol, out, M);
    }
}